// Round 6
// baseline (1825.293 us; speedup 1.0000x reference)
//
#include <hip/hip_runtime.h>
#include <cstdint>

// ---------------------------------------------------------------------------
// DDPM + VAE query encoder, MI355X round 6 (fp32)
// Root cause found (r2-r5): float Wi[64]/Wo[64] were indexed by loop vars at
// SROA time -> allocas stayed in SCRATCH; every t-step reloaded 128 weights
// from scratch (VGPR_Count=88 the whole time, ~3x issue count).
// Fix: 128 individually NAMED scalar weights via REP64 macro + fully
// macro-unrolled GEMVs with literal readlane indices. No arrays anywhere.
// amdgpu_waves_per_eu(2,2) gives the 256-VGPR budget (~190 live needed).
// Numerics identical to the passing r3/r4/r5.
// ---------------------------------------------------------------------------

#define DEVI __device__ __forceinline__

DEVI uint32_t rotl32(uint32_t x, uint32_t r) { return (x << r) | (x >> (32u - r)); }

// JAX/Random123 threefry2x32, 20 rounds.
DEVI void threefry2x32(uint32_t k0, uint32_t k1, uint32_t x0, uint32_t x1,
                       uint32_t &o0, uint32_t &o1)
{
  const uint32_t ks2 = k0 ^ k1 ^ 0x1BD11BDAu;
  x0 += k0; x1 += k1;
#define TFR(r) { x0 += x1; x1 = rotl32(x1, r); x1 ^= x0; }
  TFR(13u) TFR(15u) TFR(26u) TFR(6u)   x0 += k1;  x1 += ks2 + 1u;
  TFR(17u) TFR(29u) TFR(16u) TFR(24u)  x0 += ks2; x1 += k0 + 2u;
  TFR(13u) TFR(15u) TFR(26u) TFR(6u)   x0 += k0;  x1 += k1 + 3u;
  TFR(17u) TFR(29u) TFR(16u) TFR(24u)  x0 += k1;  x1 += ks2 + 4u;
  TFR(13u) TFR(15u) TFR(26u) TFR(6u)   x0 += ks2; x1 += k0 + 5u;
#undef TFR
  o0 = x0; o1 = x1;
}

// partitionable random_bits(32) for flat index j (size < 2^32 -> hi word 0)
DEVI uint32_t jax_random_bits32(uint32_t k0, uint32_t k1, uint32_t j)
{
  uint32_t a, b;
  threefry2x32(k0, k1, 0u, j, a, b);
  return a ^ b;
}

// bits -> uniform [-1+eps, 1) -> sqrt(2)*erfinv(u) (XLA/Giles polynomial).
DEVI float jax_bits_to_normal(uint32_t bits)
{
  const float LO = -0.99999994f;              // nextafter(-1,0) in f32
  float f = __uint_as_float((bits >> 9) | 0x3f800000u) - 1.0f;
  float u = fmaxf(LO, f * 2.0f + LO);
  float w = -__logf((1.0f - u) * (1.0f + u));
  float p;
  if (w < 5.0f) {
    w = w - 2.5f;
    p =              2.81022636e-08f;
    p = fmaf(p, w,   3.43273939e-07f);
    p = fmaf(p, w,  -3.5233877e-06f);
    p = fmaf(p, w,  -4.39150654e-06f);
    p = fmaf(p, w,   0.00021858087f);
    p = fmaf(p, w,  -0.00125372503f);
    p = fmaf(p, w,  -0.00417768164f);
    p = fmaf(p, w,   0.246640727f);
    p = fmaf(p, w,   1.50140941f);
  } else {
    w = sqrtf(w) - 3.0f;
    p =             -0.000200214257f;
    p = fmaf(p, w,   0.000100950558f);
    p = fmaf(p, w,   0.00134934322f);
    p = fmaf(p, w,  -0.00367342844f);
    p = fmaf(p, w,   0.00573950773f);
    p = fmaf(p, w,  -0.0076224613f);
    p = fmaf(p, w,   0.00943887047f);
    p = fmaf(p, w,   1.00167406f);
    p = fmaf(p, w,   2.83297682f);
  }
  return 1.41421356237f * (p * u);
}

// ---------------------------------------------------------------------------
// K_pool: 2048 blocks x 256 threads; wave per row, lane per dim.
__global__ __launch_bounds__(256)
void k_pool(const int* __restrict__ seq, const float* __restrict__ emb,
            float* __restrict__ pooled)
{
  const int lane = threadIdx.x & 63;
  const int r    = blockIdx.x * 4 + (threadIdx.x >> 6);   // 0..8191
  const int* row = seq + r * 100;
  float s = 0.f;
  int cnt = 0;
  for (int l = 0; l < 100; ++l) {
    int id = row[l];
    cnt += (id != 0);
    s += emb[id * 64 + lane];
  }
  pooled[r * 64 + lane] = s / sqrtf((float)cnt);
}

// ---------------------------------------------------------------------------
// K_enc: 1024 blocks x 256 threads; 8 rows per block.
__global__ __launch_bounds__(256)
void k_enc(const float* __restrict__ pooled,
           const float* __restrict__ W1, const float* __restrict__ b1,
           const float* __restrict__ W2, const float* __restrict__ b2,
           const float* __restrict__ Wc, const float* __restrict__ bc,
           float* __restrict__ cproj)
{
  __shared__ float p_s[8][64];
  __shared__ float h_s[8][256];
  __shared__ float mu_s[8][64];
  const int tid = threadIdx.x;
  const int r0  = blockIdx.x * 8;

  for (int i = tid; i < 8 * 64; i += 256)
    p_s[i >> 6][i & 63] = pooled[r0 * 64 + i];
  __syncthreads();

  float hacc[8];
#pragma unroll
  for (int r = 0; r < 8; ++r) hacc[r] = b1[tid];
  for (int k = 0; k < 64; ++k) {
    float w = W1[k * 256 + tid];
#pragma unroll
    for (int r = 0; r < 8; ++r) hacc[r] = fmaf(p_s[r][k], w, hacc[r]);
  }
#pragma unroll
  for (int r = 0; r < 8; ++r) h_s[r][tid] = fmaxf(hacc[r], 0.f);
  __syncthreads();

#pragma unroll
  for (int pass = 0; pass < 2; ++pass) {
    int r = pass * 4 + (tid >> 6);
    int j = tid & 63;
    float acc = b2[j];
    for (int k = 0; k < 256; ++k)
      acc = fmaf(h_s[r][k], W2[k * 128 + j], acc);
    mu_s[r][j] = acc;
  }
  __syncthreads();

#pragma unroll
  for (int pass = 0; pass < 2; ++pass) {
    int r = pass * 4 + (tid >> 6);
    int j = tid & 63;
    float acc = bc[j];
    for (int k = 0; k < 64; ++k)
      acc = fmaf(mu_s[r][k], Wc[k * 64 + j], acc);
    cproj[(r0 + r) * 64 + j] = acc;
  }
}

// ---------------------------------------------------------------------------
// K_sched: single thread, f32 mimic of the jnp schedule.
__global__ void k_sched(float* __restrict__ sched)
{
  if (threadIdx.x != 0 || blockIdx.x != 0) return;
  const float start = (float)(5.0 * 1e-4);
  const float stop  = (float)(5.0 * 0.02);
  const float delta = stop - start;
  float prod = 1.f;
  for (int i = 0; i < 200; ++i) {
    float beta  = start + ((float)i * delta) / 199.0f;
    float alpha = 1.0f - beta;
    float acp_prev = prod;
    prod = prod * alpha;
    float acp = prod;
    float om  = 1.0f - acp;
    sched[i]       = sqrtf(1.0f / acp);
    sched[200 + i] = sqrtf(1.0f / acp - 1.0f);
    sched[400 + i] = beta * sqrtf(acp_prev) / om;
    sched[600 + i] = (1.0f - acp_prev) * sqrtf(alpha) / om;
    float pv = beta * (1.0f - acp_prev) / om;
    sched[800 + i] = (i > 0) ? sqrtf(pv) : 0.0f;
  }
}

// ---------------------------------------------------------------------------
// K_tproj: 200 blocks x 64 threads; tpb[t][d] = temb(t)@W_t + b_t + b_in
__global__ __launch_bounds__(64)
void k_tproj(const float* __restrict__ Wt, const float* __restrict__ bt,
             const float* __restrict__ bin, float* __restrict__ tpb)
{
  __shared__ float temb[64];
  const int t = blockIdx.x;
  const int d = threadIdx.x;
  const float lg = logf(10000.0f);
  {
    int i = d & 31;
    float fr  = expf((-lg * (float)i) / 32.0f);
    float ang = (float)t * fr;
    temb[d] = (d < 32) ? cosf(ang) : sinf(ang);
  }
  __syncthreads();
  float acc = bt[d] + bin[d];
  for (int k = 0; k < 64; ++k)
    acc = fmaf(temb[k], Wt[k * 64 + d], acc);
  tpb[t * 64 + d] = acc;
}

// ---------------------------------------------------------------------------
// 64-entry repeat macro: M(k, q) with q = k & 3 (literal tokens only -> no
// arrays, no loop-variable indices, SROA-proof).
#define REP64Q(M) \
  M(0,0)  M(1,1)  M(2,2)  M(3,3)  M(4,0)  M(5,1)  M(6,2)  M(7,3)  \
  M(8,0)  M(9,1)  M(10,2) M(11,3) M(12,0) M(13,1) M(14,2) M(15,3) \
  M(16,0) M(17,1) M(18,2) M(19,3) M(20,0) M(21,1) M(22,2) M(23,3) \
  M(24,0) M(25,1) M(26,2) M(27,3) M(28,0) M(29,1) M(30,2) M(31,3) \
  M(32,0) M(33,1) M(34,2) M(35,3) M(36,0) M(37,1) M(38,2) M(39,3) \
  M(40,0) M(41,1) M(42,2) M(43,3) M(44,0) M(45,1) M(46,2) M(47,3) \
  M(48,0) M(49,1) M(50,2) M(51,3) M(52,0) M(53,1) M(54,2) M(55,3) \
  M(56,0) M(57,1) M(58,2) M(59,3) M(60,0) M(61,1) M(62,2) M(63,3)

#define LB(v, k) __int_as_float(__builtin_amdgcn_readlane((v), (k)))

// K_ddpm: 1024 blocks x 256 threads; wave handles rows (p, p+4096), lane = dim.
// waves_per_eu(2,2): 256-VGPR budget; ~190 live named scalars -> resident.
__global__
__attribute__((amdgpu_flat_work_group_size(256, 256), amdgpu_waves_per_eu(2, 2)))
void k_ddpm(const float* __restrict__ Win, const float* __restrict__ Wout,
            const float* __restrict__ bout,
            const float* __restrict__ cproj, const float* __restrict__ tpb,
            const float* __restrict__ sched, float* __restrict__ out)
{
  const int lane = threadIdx.x & 63;
  const int p    = blockIdx.x * 4 + (threadIdx.x >> 6);    // 0..4095
  const uint32_t jA = (uint32_t)(p * 64 + lane);           // flat idx, < 262144
  const uint32_t jB = jA + 262144u;                        // row p+4096

  // 128 individually named weight scalars (column `lane` of Win / Wout).
#define DECLW(k, q)                                                            \
  float Wi_##k = Win[(k) * 64 + lane];                                         \
  float Wo_##k = Wout[(k) * 64 + lane];
  REP64Q(DECLW)
#undef DECLW

  const float bo  = bout[lane];
  const float cpA = cproj[p * 64 + lane];
  const float cpB = cproj[(p + 4096) * 64 + lane];

  // x_init = normal(key(1)=[0,1]), partitionable bits
  float xA = jax_bits_to_normal(jax_random_bits32(0u, 1u, jA));
  float xB = jax_bits_to_normal(jax_random_bits32(0u, 1u, jB));

  const float* sr_a   = sched;
  const float* srm1_a = sched + 200;
  const float* c1_a   = sched + 400;
  const float* c2_a   = sched + 600;
  const float* sg_a   = sched + 800;

#pragma unroll 1
  for (int t = 199; t >= 0; --t) {
    // fold_in(key(2), t): wave-uniform -> SALU, overlaps VALU
    uint32_t fk0, fk1;
    threefry2x32(0u, 2u, 0u, (uint32_t)t, fk0, fk1);

    const float tp = tpb[t * 64 + lane];

    // GEMV-in: 4 rotating accumulators per row -> 8 independent FMA chains
    float aA0 = tp + cpA, aA1 = 0.f, aA2 = 0.f, aA3 = 0.f;
    float aB0 = tp + cpB, aB1 = 0.f, aB2 = 0.f, aB3 = 0.f;
    {
      const int xiA = __float_as_int(xA), xiB = __float_as_int(xB);
#define GIN(k, q)                                                              \
  aA##q = fmaf(LB(xiA, k), Wi_##k, aA##q);                                     \
  aB##q = fmaf(LB(xiB, k), Wi_##k, aB##q);
      REP64Q(GIN)
#undef GIN
    }
    float aA = (aA0 + aA1) + (aA2 + aA3);
    float aB = (aB0 + aB1) + (aB2 + aB3);

    // silu via fast rcp (~1 ulp)
    float hA = aA * __builtin_amdgcn_rcpf(1.0f + __expf(-aA));
    float hB = aB * __builtin_amdgcn_rcpf(1.0f + __expf(-aB));

    // GEMV-out
    float eA0 = bo, eA1 = 0.f, eA2 = 0.f, eA3 = 0.f;
    float eB0 = bo, eB1 = 0.f, eB2 = 0.f, eB3 = 0.f;
    {
      const int hiA = __float_as_int(hA), hiB = __float_as_int(hB);
#define GOUT(k, q)                                                             \
  eA##q = fmaf(LB(hiA, k), Wo_##k, eA##q);                                     \
  eB##q = fmaf(LB(hiB, k), Wo_##k, eB##q);
      REP64Q(GOUT)
#undef GOUT
    }
    float eA = (eA0 + eA1) + (eA2 + eA3);
    float eB = (eB0 + eB1) + (eB2 + eB3);

    const float sr = sr_a[t], srm1 = srm1_a[t];
    const float c1 = c1_a[t], c2 = c2_a[t], sg = sg_a[t];

    float x0A = fminf(1.f, fmaxf(-1.f, sr * xA - srm1 * eA));
    float x0B = fminf(1.f, fmaxf(-1.f, sr * xB - srm1 * eB));

    float nA = jax_bits_to_normal(jax_random_bits32(fk0, fk1, jA));
    float nB = jax_bits_to_normal(jax_random_bits32(fk0, fk1, jB));

    xA = c1 * x0A + c2 * xA + sg * nA;
    xB = c1 * x0B + c2 * xB + sg * nB;
  }

  out[p * 64 + lane]            = xA;
  out[(p + 4096) * 64 + lane]   = xB;
}

// ---------------------------------------------------------------------------
extern "C" void kernel_launch(void* const* d_in, const int* in_sizes, int n_in,
                              void* d_out, int out_size, void* d_ws, size_t ws_size,
                              hipStream_t stream)
{
  const int*   seq  = (const int*)  d_in[0];
  const float* emb  = (const float*)d_in[1];
  const float* W1   = (const float*)d_in[2];
  const float* b1   = (const float*)d_in[3];
  const float* W2   = (const float*)d_in[4];
  const float* b2   = (const float*)d_in[5];
  const float* Win  = (const float*)d_in[6];
  const float* bin  = (const float*)d_in[7];
  const float* Wt   = (const float*)d_in[8];
  const float* bt   = (const float*)d_in[9];
  const float* Wc   = (const float*)d_in[10];
  const float* bc   = (const float*)d_in[11];
  const float* Wout = (const float*)d_in[12];
  const float* bout = (const float*)d_in[13];

  float* out   = (float*)d_out;
  float* ws    = (float*)d_ws;
  float* cproj = ws;                       // 524288 floats
  float* tpb   = ws + 524288;              // 12800 floats
  float* sched = ws + 524288 + 12800;      // 1000 floats
  float* pooled = out;                     // reuse d_out as scratch

  k_pool <<<2048, 256, 0, stream>>>(seq, emb, pooled);
  k_enc  <<<1024, 256, 0, stream>>>(pooled, W1, b1, W2, b2, Wc, bc, cproj);
  k_sched<<<1, 64, 0, stream>>>(sched);
  k_tproj<<<200, 64, 0, stream>>>(Wt, bt, bin, tpb);
  k_ddpm <<<1024, 256, 0, stream>>>(Win, Wout, bout, cproj, tpb, sched, out);
}

// Round 7
// 1548.306 us; speedup vs baseline: 1.1789x; 1.1789x over previous
//
#include <hip/hip_runtime.h>
#include <cstdint>

// ---------------------------------------------------------------------------
// DDPM + VAE query encoder, MI355X round 7 (fp32, split-K 2-wave blocks)
// r2-r6 lesson: backend clamps this kernel to ~88 VGPRs and remat/spills any
// larger live set into the 200-step loop (immune to launch_bounds /
// waves_per_eu / asm pins / named scalars). Fix: cut per-wave weight
// residency to 64 regs by splitting K across the 2 waves of a block:
//   wave w holds Win/Wout rows k in [32w, 32w+32)  (32+32 named scalars)
//   partial sums exchanged via LDS (float2), 3 barriers/step
//   x lives in LDS; each wave reads it rotated by 32w lanes so readlane
//   indices stay literal 0..31
//   RNG: wave w owns row w (1 element/lane) - bit-identical to r3-r6
// ---------------------------------------------------------------------------

#define DEVI __device__ __forceinline__

DEVI uint32_t rotl32(uint32_t x, uint32_t r) { return (x << r) | (x >> (32u - r)); }

// JAX/Random123 threefry2x32, 20 rounds.
DEVI void threefry2x32(uint32_t k0, uint32_t k1, uint32_t x0, uint32_t x1,
                       uint32_t &o0, uint32_t &o1)
{
  const uint32_t ks2 = k0 ^ k1 ^ 0x1BD11BDAu;
  x0 += k0; x1 += k1;
#define TFR(r) { x0 += x1; x1 = rotl32(x1, r); x1 ^= x0; }
  TFR(13u) TFR(15u) TFR(26u) TFR(6u)   x0 += k1;  x1 += ks2 + 1u;
  TFR(17u) TFR(29u) TFR(16u) TFR(24u)  x0 += ks2; x1 += k0 + 2u;
  TFR(13u) TFR(15u) TFR(26u) TFR(6u)   x0 += k0;  x1 += k1 + 3u;
  TFR(17u) TFR(29u) TFR(16u) TFR(24u)  x0 += k1;  x1 += ks2 + 4u;
  TFR(13u) TFR(15u) TFR(26u) TFR(6u)   x0 += ks2; x1 += k0 + 5u;
#undef TFR
  o0 = x0; o1 = x1;
}

// partitionable random_bits(32) for flat index j (size < 2^32 -> hi word 0)
DEVI uint32_t jax_random_bits32(uint32_t k0, uint32_t k1, uint32_t j)
{
  uint32_t a, b;
  threefry2x32(k0, k1, 0u, j, a, b);
  return a ^ b;
}

// bits -> uniform [-1+eps, 1) -> sqrt(2)*erfinv(u) (XLA/Giles polynomial).
DEVI float jax_bits_to_normal(uint32_t bits)
{
  const float LO = -0.99999994f;              // nextafter(-1,0) in f32
  float f = __uint_as_float((bits >> 9) | 0x3f800000u) - 1.0f;
  float u = fmaxf(LO, f * 2.0f + LO);
  float w = -__logf((1.0f - u) * (1.0f + u));
  float p;
  if (w < 5.0f) {
    w = w - 2.5f;
    p =              2.81022636e-08f;
    p = fmaf(p, w,   3.43273939e-07f);
    p = fmaf(p, w,  -3.5233877e-06f);
    p = fmaf(p, w,  -4.39150654e-06f);
    p = fmaf(p, w,   0.00021858087f);
    p = fmaf(p, w,  -0.00125372503f);
    p = fmaf(p, w,  -0.00417768164f);
    p = fmaf(p, w,   0.246640727f);
    p = fmaf(p, w,   1.50140941f);
  } else {
    w = sqrtf(w) - 3.0f;
    p =             -0.000200214257f;
    p = fmaf(p, w,   0.000100950558f);
    p = fmaf(p, w,   0.00134934322f);
    p = fmaf(p, w,  -0.00367342844f);
    p = fmaf(p, w,   0.00573950773f);
    p = fmaf(p, w,  -0.0076224613f);
    p = fmaf(p, w,   0.00943887047f);
    p = fmaf(p, w,   1.00167406f);
    p = fmaf(p, w,   2.83297682f);
  }
  return 1.41421356237f * (p * u);
}

// ---------------------------------------------------------------------------
// K_pool: 2048 blocks x 256 threads; wave per row, lane per dim.
__global__ __launch_bounds__(256)
void k_pool(const int* __restrict__ seq, const float* __restrict__ emb,
            float* __restrict__ pooled)
{
  const int lane = threadIdx.x & 63;
  const int r    = blockIdx.x * 4 + (threadIdx.x >> 6);   // 0..8191
  const int* row = seq + r * 100;
  float s = 0.f;
  int cnt = 0;
  for (int l = 0; l < 100; ++l) {
    int id = row[l];
    cnt += (id != 0);
    s += emb[id * 64 + lane];
  }
  pooled[r * 64 + lane] = s / sqrtf((float)cnt);
}

// ---------------------------------------------------------------------------
// K_enc: 1024 blocks x 256 threads; 8 rows per block.
__global__ __launch_bounds__(256)
void k_enc(const float* __restrict__ pooled,
           const float* __restrict__ W1, const float* __restrict__ b1,
           const float* __restrict__ W2, const float* __restrict__ b2,
           const float* __restrict__ Wc, const float* __restrict__ bc,
           float* __restrict__ cproj)
{
  __shared__ float p_s[8][64];
  __shared__ float h_s[8][256];
  __shared__ float mu_s[8][64];
  const int tid = threadIdx.x;
  const int r0  = blockIdx.x * 8;

  for (int i = tid; i < 8 * 64; i += 256)
    p_s[i >> 6][i & 63] = pooled[r0 * 64 + i];
  __syncthreads();

  float hacc[8];
#pragma unroll
  for (int r = 0; r < 8; ++r) hacc[r] = b1[tid];
  for (int k = 0; k < 64; ++k) {
    float w = W1[k * 256 + tid];
#pragma unroll
    for (int r = 0; r < 8; ++r) hacc[r] = fmaf(p_s[r][k], w, hacc[r]);
  }
#pragma unroll
  for (int r = 0; r < 8; ++r) h_s[r][tid] = fmaxf(hacc[r], 0.f);
  __syncthreads();

#pragma unroll
  for (int pass = 0; pass < 2; ++pass) {
    int r = pass * 4 + (tid >> 6);
    int j = tid & 63;
    float acc = b2[j];
    for (int k = 0; k < 256; ++k)
      acc = fmaf(h_s[r][k], W2[k * 128 + j], acc);
    mu_s[r][j] = acc;
  }
  __syncthreads();

#pragma unroll
  for (int pass = 0; pass < 2; ++pass) {
    int r = pass * 4 + (tid >> 6);
    int j = tid & 63;
    float acc = bc[j];
    for (int k = 0; k < 64; ++k)
      acc = fmaf(mu_s[r][k], Wc[k * 64 + j], acc);
    cproj[(r0 + r) * 64 + j] = acc;
  }
}

// ---------------------------------------------------------------------------
// K_sched: single thread; layout sched[t*8 + {0:sr,1:srm1,2:c1,3:c2,4:sg}]
__global__ void k_sched(float* __restrict__ sched)
{
  if (threadIdx.x != 0 || blockIdx.x != 0) return;
  const float start = (float)(5.0 * 1e-4);
  const float stop  = (float)(5.0 * 0.02);
  const float delta = stop - start;
  float prod = 1.f;
  for (int i = 0; i < 200; ++i) {
    float beta  = start + ((float)i * delta) / 199.0f;
    float alpha = 1.0f - beta;
    float acp_prev = prod;
    prod = prod * alpha;
    float acp = prod;
    float om  = 1.0f - acp;
    sched[i * 8 + 0] = sqrtf(1.0f / acp);
    sched[i * 8 + 1] = sqrtf(1.0f / acp - 1.0f);
    sched[i * 8 + 2] = beta * sqrtf(acp_prev) / om;
    sched[i * 8 + 3] = (1.0f - acp_prev) * sqrtf(alpha) / om;
    float pv = beta * (1.0f - acp_prev) / om;
    sched[i * 8 + 4] = (i > 0) ? sqrtf(pv) : 0.0f;
  }
}

// ---------------------------------------------------------------------------
// K_tproj: 200 blocks x 64 threads; tpb[t][d] = temb(t)@W_t + b_t + b_in
__global__ __launch_bounds__(64)
void k_tproj(const float* __restrict__ Wt, const float* __restrict__ bt,
             const float* __restrict__ bin, float* __restrict__ tpb)
{
  __shared__ float temb[64];
  const int t = blockIdx.x;
  const int d = threadIdx.x;
  const float lg = logf(10000.0f);
  {
    int i = d & 31;
    float fr  = expf((-lg * (float)i) / 32.0f);
    float ang = (float)t * fr;
    temb[d] = (d < 32) ? cosf(ang) : sinf(ang);
  }
  __syncthreads();
  float acc = bt[d] + bin[d];
  for (int k = 0; k < 64; ++k)
    acc = fmaf(temb[k], Wt[k * 64 + d], acc);
  tpb[t * 64 + d] = acc;
}

// ---------------------------------------------------------------------------
// 32-entry repeat macro: M(j, q) with q = j & 1 (literal tokens only).
#define REP32Q(M) \
  M(0,0)  M(1,1)  M(2,0)  M(3,1)  M(4,0)  M(5,1)  M(6,0)  M(7,1)  \
  M(8,0)  M(9,1)  M(10,0) M(11,1) M(12,0) M(13,1) M(14,0) M(15,1) \
  M(16,0) M(17,1) M(18,0) M(19,1) M(20,0) M(21,1) M(22,0) M(23,1) \
  M(24,0) M(25,1) M(26,0) M(27,1) M(28,0) M(29,1) M(30,0) M(31,1)

#define LB(v, k) __int_as_float(__builtin_amdgcn_readlane((v), (k)))

// K_ddpm: 4096 blocks x 128 threads (2 waves). Block owns rows (2b, 2b+1).
// Wave w holds k-slice [32w,32w+32) of Win and Wout (64 fp32 regs).
__global__ __launch_bounds__(128)
void k_ddpm(const float* __restrict__ Win, const float* __restrict__ Wout,
            const float* __restrict__ bout,
            const float* __restrict__ cproj, const float* __restrict__ tpb,
            const float* __restrict__ sched, float* __restrict__ out)
{
  __shared__ float2 hp[2][64];   // [wave][out-dim] -> (row0, row1) h partials
  __shared__ float2 ep[2][64];   // [wave][out-dim] -> (row0, row1) eps partials
  __shared__ float  xb[2][64];   // [row][dim] canonical x state

  const int lane = threadIdx.x & 63;
  const int warp = threadIdx.x >> 6;          // 0 or 1
  const int dd   = (lane + (warp << 5)) & 63; // rotated dim for x/h reads
  const int r0g  = blockIdx.x * 2;            // global row of row0
  const int kb   = warp << 5;                 // k-slice base

  // named weight scalars: Wi_j = Win[(kb+j)*64 + lane], same for Wout
#define DECLW(j, q)                                                            \
  float Wi_##j = Win [(kb + j) * 64 + lane];                                   \
  float Wo_##j = Wout[(kb + j) * 64 + lane];
  REP32Q(DECLW)
#undef DECLW

  const float bo  = bout[lane];
  const float cp0 = cproj[(r0g + 0) * 64 + lane];
  const float cp1 = cproj[(r0g + 1) * 64 + lane];
  const bool  w0  = (warp == 0);

  // x_init: wave w initializes row w, element (row, lane)
  {
    uint32_t j = (uint32_t)((r0g + warp) * 64 + lane);
    xb[warp][lane] = jax_bits_to_normal(jax_random_bits32(0u, 1u, j));
  }
  __syncthreads();
  float x0 = xb[0][dd];       // rotated copies for readlane-literal GEMV
  float x1 = xb[1][dd];

#pragma unroll 1
  for (int t = 199; t >= 0; --t) {
    // fold_in(key(2), t): wave-uniform
    uint32_t fk0, fk1;
    threefry2x32(0u, 2u, 0u, (uint32_t)t, fk0, fk1);

    const float tp = tpb[t * 64 + lane];

    // ---- GEMV-in partials over own k-slice (init carries tp+cp on wave0)
    float aA0 = w0 ? (tp + cp0) : 0.f, aA1 = 0.f;
    float aB0 = w0 ? (tp + cp1) : 0.f, aB1 = 0.f;
    {
      const int x0i = __float_as_int(x0), x1i = __float_as_int(x1);
#define GIN(j, q)                                                              \
  aA##q = fmaf(LB(x0i, j), Wi_##j, aA##q);                                     \
  aB##q = fmaf(LB(x1i, j), Wi_##j, aB##q);
      REP32Q(GIN)
#undef GIN
    }
    hp[warp][lane] = make_float2(aA0 + aA1, aB0 + aB1);
    __syncthreads();                                        // B1

    // ---- reduce h at rotated dim, silu
    float2 ha = hp[0][dd], hb = hp[1][dd];
    float h0 = ha.x + hb.x;
    float h1 = ha.y + hb.y;
    h0 = h0 * __builtin_amdgcn_rcpf(1.0f + __expf(-h0));
    h1 = h1 * __builtin_amdgcn_rcpf(1.0f + __expf(-h1));

    // ---- GEMV-out partials over own k-slice (init carries bo on wave0)
    float eA0 = w0 ? bo : 0.f, eA1 = 0.f;
    float eB0 = w0 ? bo : 0.f, eB1 = 0.f;
    {
      const int h0i = __float_as_int(h0), h1i = __float_as_int(h1);
#define GOUT(j, q)                                                             \
  eA##q = fmaf(LB(h0i, j), Wo_##j, eA##q);                                     \
  eB##q = fmaf(LB(h1i, j), Wo_##j, eB##q);
      REP32Q(GOUT)
#undef GOUT
    }
    float epA = eA0 + eA1, epB = eB0 + eB1;
    ep[warp][lane] = make_float2(epA, epB);
    __syncthreads();                                        // B2

    // ---- wave w finalizes eps for row w at unrotated dim, updates row w
    float own   = warp ? epB : epA;
    float other = ((const float*)&ep[1 - warp][lane])[warp];
    float eps   = own + other;

    float xold = xb[warp][lane];

    const float sr   = sched[t * 8 + 0];
    const float srm1 = sched[t * 8 + 1];
    const float c1   = sched[t * 8 + 2];
    const float c2   = sched[t * 8 + 3];
    const float sg   = sched[t * 8 + 4];

    float x0c = fminf(1.f, fmaxf(-1.f, sr * xold - srm1 * eps));
    uint32_t j = (uint32_t)((r0g + warp) * 64 + lane);
    float n   = jax_bits_to_normal(jax_random_bits32(fk0, fk1, j));
    float xn  = c1 * x0c + c2 * xold + sg * n;

    xb[warp][lane] = xn;
    __syncthreads();                                        // B3

    x0 = xb[0][dd];
    x1 = xb[1][dd];
  }

  // wave w stores row w (own writes, no barrier needed)
  out[(r0g + warp) * 64 + lane] = xb[warp][lane];
}

// ---------------------------------------------------------------------------
extern "C" void kernel_launch(void* const* d_in, const int* in_sizes, int n_in,
                              void* d_out, int out_size, void* d_ws, size_t ws_size,
                              hipStream_t stream)
{
  const int*   seq  = (const int*)  d_in[0];
  const float* emb  = (const float*)d_in[1];
  const float* W1   = (const float*)d_in[2];
  const float* b1   = (const float*)d_in[3];
  const float* W2   = (const float*)d_in[4];
  const float* b2   = (const float*)d_in[5];
  const float* Win  = (const float*)d_in[6];
  const float* bin  = (const float*)d_in[7];
  const float* Wt   = (const float*)d_in[8];
  const float* bt   = (const float*)d_in[9];
  const float* Wc   = (const float*)d_in[10];
  const float* bc   = (const float*)d_in[11];
  const float* Wout = (const float*)d_in[12];
  const float* bout = (const float*)d_in[13];

  float* out   = (float*)d_out;
  float* ws    = (float*)d_ws;
  float* cproj = ws;                       // 524288 floats
  float* tpb   = ws + 524288;              // 12800 floats
  float* sched = ws + 524288 + 12800;      // 1600 floats (t*8 layout)
  float* pooled = out;                     // reuse d_out as scratch

  k_pool <<<2048, 256, 0, stream>>>(seq, emb, pooled);
  k_enc  <<<1024, 256, 0, stream>>>(pooled, W1, b1, W2, b2, Wc, bc, cproj);
  k_sched<<<1, 64, 0, stream>>>(sched);
  k_tproj<<<200, 64, 0, stream>>>(Wt, bt, bin, tpb);
  k_ddpm <<<4096, 128, 0, stream>>>(Win, Wout, bout, cproj, tpb, sched, out);
}

// Round 8
// 835.066 us; speedup vs baseline: 2.1858x; 1.8541x over previous
//
#include <hip/hip_runtime.h>
#include <cstdint>

// ---------------------------------------------------------------------------
// DDPM + VAE query encoder, MI355X round 8: MFMA (hi/lo bf16 split) ddpm loop.
// r2-r7 lesson: the backend clamps this kernel family to ~80-88 VGPRs and
// serves any larger live set with in-loop reloads (immune to launch_bounds /
// waves_per_eu / asm pins / named scalars / split-K). So: shrink the demand.
// Weights as bf16 hi/lo MFMA B-fragments = 32 VGPRs. X/H staged in LDS as
// bf16 hi+lo; X@W = Ah*Bh + Ah*Bl + Al*Bh (fp32 acc, ~2^-16 rel error).
// RNG element assignment == MFMA C-layout (col=lane&15, row=quad*4+reg), so
// eps stays in registers and threefry bits are identical to r2-r7.
// ---------------------------------------------------------------------------

#define DEVI __device__ __forceinline__

typedef __attribute__((ext_vector_type(8))) short short8;
typedef __attribute__((ext_vector_type(4))) float f32x4;

DEVI uint32_t rotl32(uint32_t x, uint32_t r) { return (x << r) | (x >> (32u - r)); }

// JAX/Random123 threefry2x32, 20 rounds.
DEVI void threefry2x32(uint32_t k0, uint32_t k1, uint32_t x0, uint32_t x1,
                       uint32_t &o0, uint32_t &o1)
{
  const uint32_t ks2 = k0 ^ k1 ^ 0x1BD11BDAu;
  x0 += k0; x1 += k1;
#define TFR(r) { x0 += x1; x1 = rotl32(x1, r); x1 ^= x0; }
  TFR(13u) TFR(15u) TFR(26u) TFR(6u)   x0 += k1;  x1 += ks2 + 1u;
  TFR(17u) TFR(29u) TFR(16u) TFR(24u)  x0 += ks2; x1 += k0 + 2u;
  TFR(13u) TFR(15u) TFR(26u) TFR(6u)   x0 += k0;  x1 += k1 + 3u;
  TFR(17u) TFR(29u) TFR(16u) TFR(24u)  x0 += k1;  x1 += ks2 + 4u;
  TFR(13u) TFR(15u) TFR(26u) TFR(6u)   x0 += ks2; x1 += k0 + 5u;
#undef TFR
  o0 = x0; o1 = x1;
}

DEVI uint32_t jax_random_bits32(uint32_t k0, uint32_t k1, uint32_t j)
{
  uint32_t a, b;
  threefry2x32(k0, k1, 0u, j, a, b);
  return a ^ b;
}

// bits -> uniform [-1+eps, 1) -> sqrt(2)*erfinv(u) (XLA/Giles polynomial).
DEVI float jax_bits_to_normal(uint32_t bits)
{
  const float LO = -0.99999994f;
  float f = __uint_as_float((bits >> 9) | 0x3f800000u) - 1.0f;
  float u = fmaxf(LO, f * 2.0f + LO);
  float w = -__logf((1.0f - u) * (1.0f + u));
  float p;
  if (w < 5.0f) {
    w = w - 2.5f;
    p =              2.81022636e-08f;
    p = fmaf(p, w,   3.43273939e-07f);
    p = fmaf(p, w,  -3.5233877e-06f);
    p = fmaf(p, w,  -4.39150654e-06f);
    p = fmaf(p, w,   0.00021858087f);
    p = fmaf(p, w,  -0.00125372503f);
    p = fmaf(p, w,  -0.00417768164f);
    p = fmaf(p, w,   0.246640727f);
    p = fmaf(p, w,   1.50140941f);
  } else {
    w = sqrtf(w) - 3.0f;
    p =             -0.000200214257f;
    p = fmaf(p, w,   0.000100950558f);
    p = fmaf(p, w,   0.00134934322f);
    p = fmaf(p, w,  -0.00367342844f);
    p = fmaf(p, w,   0.00573950773f);
    p = fmaf(p, w,  -0.0076224613f);
    p = fmaf(p, w,   0.00943887047f);
    p = fmaf(p, w,   1.00167406f);
    p = fmaf(p, w,   2.83297682f);
  }
  return 1.41421356237f * (p * u);
}

// truncation-based fp32 -> bf16 hi + bf16 lo split (residual <= 2^-16 |x|)
DEVI short bf16_hi_trunc(float x) { return (short)(__float_as_uint(x) >> 16); }
DEVI float bf16_to_f32(short h)
{
  return __uint_as_float(((uint32_t)(unsigned short)h) << 16);
}
DEVI void split_bf16(float x, short &h, short &l)
{
  h = bf16_hi_trunc(x);
  float r = x - bf16_to_f32(h);
  l = bf16_hi_trunc(r);
}

// ---------------------------------------------------------------------------
// K_pool: 2048 blocks x 256 threads; wave per row, lane per dim.
__global__ __launch_bounds__(256)
void k_pool(const int* __restrict__ seq, const float* __restrict__ emb,
            float* __restrict__ pooled)
{
  const int lane = threadIdx.x & 63;
  const int r    = blockIdx.x * 4 + (threadIdx.x >> 6);
  const int* row = seq + r * 100;
  float s = 0.f;
  int cnt = 0;
  for (int l = 0; l < 100; ++l) {
    int id = row[l];
    cnt += (id != 0);
    s += emb[id * 64 + lane];
  }
  pooled[r * 64 + lane] = s / sqrtf((float)cnt);
}

// ---------------------------------------------------------------------------
// K_enc: 1024 blocks x 256 threads; 8 rows per block.
__global__ __launch_bounds__(256)
void k_enc(const float* __restrict__ pooled,
           const float* __restrict__ W1, const float* __restrict__ b1,
           const float* __restrict__ W2, const float* __restrict__ b2,
           const float* __restrict__ Wc, const float* __restrict__ bc,
           float* __restrict__ cproj)
{
  __shared__ float p_s[8][64];
  __shared__ float h_s[8][256];
  __shared__ float mu_s[8][64];
  const int tid = threadIdx.x;
  const int r0  = blockIdx.x * 8;

  for (int i = tid; i < 8 * 64; i += 256)
    p_s[i >> 6][i & 63] = pooled[r0 * 64 + i];
  __syncthreads();

  float hacc[8];
#pragma unroll
  for (int r = 0; r < 8; ++r) hacc[r] = b1[tid];
  for (int k = 0; k < 64; ++k) {
    float w = W1[k * 256 + tid];
#pragma unroll
    for (int r = 0; r < 8; ++r) hacc[r] = fmaf(p_s[r][k], w, hacc[r]);
  }
#pragma unroll
  for (int r = 0; r < 8; ++r) h_s[r][tid] = fmaxf(hacc[r], 0.f);
  __syncthreads();

#pragma unroll
  for (int pass = 0; pass < 2; ++pass) {
    int r = pass * 4 + (tid >> 6);
    int j = tid & 63;
    float acc = b2[j];
    for (int k = 0; k < 256; ++k)
      acc = fmaf(h_s[r][k], W2[k * 128 + j], acc);
    mu_s[r][j] = acc;
  }
  __syncthreads();

#pragma unroll
  for (int pass = 0; pass < 2; ++pass) {
    int r = pass * 4 + (tid >> 6);
    int j = tid & 63;
    float acc = bc[j];
    for (int k = 0; k < 64; ++k)
      acc = fmaf(mu_s[r][k], Wc[k * 64 + j], acc);
    cproj[(r0 + r) * 64 + j] = acc;
  }
}

// ---------------------------------------------------------------------------
// K_sched: single thread; layout sched[t*8 + {0:sr,1:srm1,2:c1,3:c2,4:sg}]
__global__ void k_sched(float* __restrict__ sched)
{
  if (threadIdx.x != 0 || blockIdx.x != 0) return;
  const float start = (float)(5.0 * 1e-4);
  const float stop  = (float)(5.0 * 0.02);
  const float delta = stop - start;
  float prod = 1.f;
  for (int i = 0; i < 200; ++i) {
    float beta  = start + ((float)i * delta) / 199.0f;
    float alpha = 1.0f - beta;
    float acp_prev = prod;
    prod = prod * alpha;
    float acp = prod;
    float om  = 1.0f - acp;
    sched[i * 8 + 0] = sqrtf(1.0f / acp);
    sched[i * 8 + 1] = sqrtf(1.0f / acp - 1.0f);
    sched[i * 8 + 2] = beta * sqrtf(acp_prev) / om;
    sched[i * 8 + 3] = (1.0f - acp_prev) * sqrtf(alpha) / om;
    float pv = beta * (1.0f - acp_prev) / om;
    sched[i * 8 + 4] = (i > 0) ? sqrtf(pv) : 0.0f;
  }
}

// ---------------------------------------------------------------------------
// K_tproj: 200 blocks x 64 threads; tpb[t][d] = temb(t)@W_t + b_t + b_in
__global__ __launch_bounds__(64)
void k_tproj(const float* __restrict__ Wt, const float* __restrict__ bt,
             const float* __restrict__ bin, float* __restrict__ tpb)
{
  __shared__ float temb[64];
  const int t = blockIdx.x;
  const int d = threadIdx.x;
  const float lg = logf(10000.0f);
  {
    int i = d & 31;
    float fr  = expf((-lg * (float)i) / 32.0f);
    float ang = (float)t * fr;
    temb[d] = (d < 32) ? cosf(ang) : sinf(ang);
  }
  __syncthreads();
  float acc = bt[d] + bin[d];
  for (int k = 0; k < 64; ++k)
    acc = fmaf(temb[k], Wt[k * 64 + d], acc);
  tpb[t * 64 + d] = acc;
}

// ---------------------------------------------------------------------------
// K_ddpm: 512 blocks x 256 threads (4 waves). Block owns 16 rows.
// Wave w computes N-tile cols [16w,16w+16) of both GEMVs via MFMA.
// Thread (wave w, lane l) owns elements (row=quad*4+i, dim=16w+(l&15)).
#define LDSTRIDE 72   // shorts per row: 144 B, 16B-aligned, bank-spreading

__global__ __launch_bounds__(256)
void k_ddpm(const float* __restrict__ Win, const float* __restrict__ Wout,
            const float* __restrict__ bout,
            const float* __restrict__ cproj, const float* __restrict__ tpb,
            const float* __restrict__ sched, float* __restrict__ out)
{
  __shared__ short Xh[16 * LDSTRIDE], Xl[16 * LDSTRIDE];
  __shared__ short Hh[16 * LDSTRIDE], Hl[16 * LDSTRIDE];

  const int lane = threadIdx.x & 63;
  const int wv   = threadIdx.x >> 6;     // 0..3 : N-tile
  const int nn   = lane & 15;
  const int quad = lane >> 4;
  const int dim  = wv * 16 + nn;         // global hidden/output dim
  const int rowq = quad * 4;             // rows rowq..rowq+3 in C-layout
  const int r0g  = blockIdx.x * 16;      // block's first batch row
  const int arow = lane & 15;            // A-fragment row (m)

  // ---- weight B-fragments: lane holds B[k = 32c+quad*8+j][n = dim], bf16 hi/lo
  short8 WiH[2], WiL[2], WoH[2], WoL[2];
#pragma unroll
  for (int c = 0; c < 2; ++c) {
#pragma unroll
    for (int j = 0; j < 8; ++j) {
      int k = c * 32 + quad * 8 + j;
      short h, l;
      split_bf16(Win[k * 64 + dim], h, l);
      WiH[c][j] = h; WiL[c][j] = l;
      split_bf16(Wout[k * 64 + dim], h, l);
      WoH[c][j] = h; WoL[c][j] = l;
    }
  }

  const float bo = bout[dim];
  float cp[4];
  uint32_t jj[4];
#pragma unroll
  for (int i = 0; i < 4; ++i) {
    cp[i] = cproj[(r0g + rowq + i) * 64 + dim];
    jj[i] = (uint32_t)((r0g + rowq + i) * 64 + dim);
  }

  // ---- x_init = normal(key(1)=[0,1]) at owned positions
  float xo[4];
#pragma unroll
  for (int i = 0; i < 4; ++i)
    xo[i] = jax_bits_to_normal(jax_random_bits32(0u, 1u, jj[i]));
#pragma unroll
  for (int i = 0; i < 4; ++i) {
    short h, l;
    split_bf16(xo[i], h, l);
    Xh[(rowq + i) * LDSTRIDE + dim] = h;
    Xl[(rowq + i) * LDSTRIDE + dim] = l;
  }
  __syncthreads();

#pragma unroll 1
  for (int t = 199; t >= 0; --t) {
    uint32_t fk0, fk1;
    threefry2x32(0u, 2u, 0u, (uint32_t)t, fk0, fk1);     // wave-uniform

    const float tp = tpb[t * 64 + dim];

    // ---- in-GEMV: A = X(16x64) @ Win(64x64), this wave's 16-col tile
    f32x4 acc;
#pragma unroll
    for (int i = 0; i < 4; ++i) acc[i] = tp + cp[i];
#pragma unroll
    for (int c = 0; c < 2; ++c) {
      short8 ah = *(const short8*)&Xh[arow * LDSTRIDE + c * 32 + quad * 8];
      short8 al = *(const short8*)&Xl[arow * LDSTRIDE + c * 32 + quad * 8];
      acc = __builtin_amdgcn_mfma_f32_16x16x32_bf16(al, WiH[c], acc, 0, 0, 0);
      acc = __builtin_amdgcn_mfma_f32_16x16x32_bf16(ah, WiL[c], acc, 0, 0, 0);
      acc = __builtin_amdgcn_mfma_f32_16x16x32_bf16(ah, WiH[c], acc, 0, 0, 0);
    }

    // ---- silu, restage H
#pragma unroll
    for (int i = 0; i < 4; ++i) {
      float a = acc[i];
      float h = a * __builtin_amdgcn_rcpf(1.0f + __expf(-a));
      short hh, hl;
      split_bf16(h, hh, hl);
      Hh[(rowq + i) * LDSTRIDE + dim] = hh;
      Hl[(rowq + i) * LDSTRIDE + dim] = hl;
    }
    __syncthreads();                                      // B2

    // ---- out-GEMV: eps = H @ Wout + bout
    f32x4 eac;
#pragma unroll
    for (int i = 0; i < 4; ++i) eac[i] = bo;
#pragma unroll
    for (int c = 0; c < 2; ++c) {
      short8 ah = *(const short8*)&Hh[arow * LDSTRIDE + c * 32 + quad * 8];
      short8 al = *(const short8*)&Hl[arow * LDSTRIDE + c * 32 + quad * 8];
      eac = __builtin_amdgcn_mfma_f32_16x16x32_bf16(al, WoH[c], eac, 0, 0, 0);
      eac = __builtin_amdgcn_mfma_f32_16x16x32_bf16(ah, WoL[c], eac, 0, 0, 0);
      eac = __builtin_amdgcn_mfma_f32_16x16x32_bf16(ah, WoH[c], eac, 0, 0, 0);
    }

    const float sr   = sched[t * 8 + 0];
    const float srm1 = sched[t * 8 + 1];
    const float c1   = sched[t * 8 + 2];
    const float c2   = sched[t * 8 + 3];
    const float sg   = sched[t * 8 + 4];

    // ---- per-element update + RNG (eps already in registers, C-layout)
#pragma unroll
    for (int i = 0; i < 4; ++i) {
      float x0c = fminf(1.f, fmaxf(-1.f, sr * xo[i] - srm1 * eac[i]));
      float n   = jax_bits_to_normal(jax_random_bits32(fk0, fk1, jj[i]));
      xo[i]     = c1 * x0c + c2 * xo[i] + sg * n;
    }

    // ---- restage X for next step
#pragma unroll
    for (int i = 0; i < 4; ++i) {
      short h, l;
      split_bf16(xo[i], h, l);
      Xh[(rowq + i) * LDSTRIDE + dim] = h;
      Xl[(rowq + i) * LDSTRIDE + dim] = l;
    }
    __syncthreads();                                      // B3
  }

  // ---- final store (owned positions)
#pragma unroll
  for (int i = 0; i < 4; ++i)
    out[(r0g + rowq + i) * 64 + dim] = xo[i];
}

// ---------------------------------------------------------------------------
extern "C" void kernel_launch(void* const* d_in, const int* in_sizes, int n_in,
                              void* d_out, int out_size, void* d_ws, size_t ws_size,
                              hipStream_t stream)
{
  const int*   seq  = (const int*)  d_in[0];
  const float* emb  = (const float*)d_in[1];
  const float* W1   = (const float*)d_in[2];
  const float* b1   = (const float*)d_in[3];
  const float* W2   = (const float*)d_in[4];
  const float* b2   = (const float*)d_in[5];
  const float* Win  = (const float*)d_in[6];
  const float* bin  = (const float*)d_in[7];
  const float* Wt   = (const float*)d_in[8];
  const float* bt   = (const float*)d_in[9];
  const float* Wc   = (const float*)d_in[10];
  const float* bc   = (const float*)d_in[11];
  const float* Wout = (const float*)d_in[12];
  const float* bout = (const float*)d_in[13];

  float* out   = (float*)d_out;
  float* ws    = (float*)d_ws;
  float* cproj = ws;                       // 524288 floats
  float* tpb   = ws + 524288;              // 12800 floats
  float* sched = ws + 524288 + 12800;      // 1600 floats (t*8 layout)
  float* pooled = out;                     // reuse d_out as scratch

  k_pool <<<2048, 256, 0, stream>>>(seq, emb, pooled);
  k_enc  <<<1024, 256, 0, stream>>>(pooled, W1, b1, W2, b2, Wc, bc, cproj);
  k_sched<<<1, 64, 0, stream>>>(sched);
  k_tproj<<<200, 64, 0, stream>>>(Wt, bt, bin, tpb);
  k_ddpm <<<512, 256, 0, stream>>>(Win, Wout, bout, cproj, tpb, sched, out);
}